// Round 12
// baseline (372.214 us; speedup 1.0000x reference)
//
#include <hip/hip_runtime.h>
#include <hip/hip_bf16.h>
#include <math.h>

#define HEADS 3
#define HO 384
#define NGRAPH 64
#define F_IN 256
#define SLOPE 0.2f

typedef __attribute__((ext_vector_type(8))) short bf8;
typedef __attribute__((ext_vector_type(4))) float f4;

// ---- bf16 helpers ----
__device__ __forceinline__ unsigned short bfr(float f) {
    unsigned u = __float_as_uint(f);
    u += 0x7fffu + ((u >> 16) & 1u);
    return (unsigned short)(u >> 16);
}
__device__ __forceinline__ float bflo(unsigned u) { return __uint_as_float(u << 16); }
__device__ __forceinline__ float bfhi(unsigned u) { return __uint_as_float(u & 0xffff0000u); }
__device__ __forceinline__ float lrelu(float v) { return (v > 0.f) ? v : SLOPE * v; }

// ---- K0: fused misc pre-pass (block-range dispatch) ----
__global__ __launch_bounds__(256) void misc_k(const int* __restrict__ ei,
                                              const float* __restrict__ W,
                                              const int* __restrict__ batch,
                                              int* __restrict__ count,
                                              int* __restrict__ rank,
                                              short* __restrict__ WbT,
                                              int* __restrict__ gstart,
                                              int NBc, int E, int N) {
    int b = blockIdx.x;
    if (b < NBc) {
        int e = b * 256 + threadIdx.x;
        int ET = E + N;
        if (e >= ET) return;
        int d = (e < E) ? ei[E + e] : (e - E);
        rank[e] = atomicAdd(&count[d], 1);   // unique within-dst rank
    } else if (b < NBc + 384) {
        int n = b - NBc;
        int k = threadIdx.x;
        WbT[n * 256 + k] = (short)bfr(W[(size_t)k * HO + n]);
    } else {
        int g = threadIdx.x;
        if (g > NGRAPH) return;
        int lo = 0, hi = N;
        while (lo < hi) { int mid = (lo + hi) >> 1; if (batch[mid] < g) lo = mid + 1; else hi = mid; }
        gstart[g] = lo;
    }
}

// ---- K1: LDS-staged bf16 MFMA GEMM + attention-dot epilogue (round-9 proven
// config: 256 thr, X+B staged in LDS, X register-prefetched one chunk ahead) ----
#define XS_STRIDE 40
__global__ __launch_bounds__(256, 3) void gemm_att(const float* __restrict__ X,
                                                   const short* __restrict__ WbT,
                                                   const float* __restrict__ att_src,
                                                   const float* __restrict__ att_dst,
                                                   unsigned* __restrict__ Hb,
                                                   float* __restrict__ aSrcO,
                                                   float* __restrict__ aDstO, int N) {
    __shared__ short Xs[64 * XS_STRIDE];
    __shared__ short Bs[384 * XS_STRIDE];
    __shared__ float lsS[64][8];
    __shared__ float lsD[64][8];
    int t = threadIdx.x;
    int w = t >> 6, lane = t & 63;
    int quad = lane >> 4, l15 = lane & 15;
    int rbase = blockIdx.x * 64;

    int sr = t >> 2;             // 0..63 (X row)
    int sko = (t & 3) * 8;       // 0,8,16,24
    int xrow = rbase + sr;
    xrow = (xrow < N) ? xrow : (N - 1);   // clamped rows never stored
    const float* xrp = X + (size_t)xrow * F_IN;

    f4 acc[4][6] = {};

    float4 p0 = *(const float4*)(xrp + sko);
    float4 p1 = *(const float4*)(xrp + sko + 4);

    for (int k0 = 0; k0 < F_IN; k0 += 32) {
        __syncthreads();
        {
            bf8 pk;
            pk[0] = (short)bfr(p0.x); pk[1] = (short)bfr(p0.y);
            pk[2] = (short)bfr(p0.z); pk[3] = (short)bfr(p0.w);
            pk[4] = (short)bfr(p1.x); pk[5] = (short)bfr(p1.y);
            pk[6] = (short)bfr(p1.z); pk[7] = (short)bfr(p1.w);
            *(bf8*)(&Xs[sr * XS_STRIDE + sko]) = pk;
        }
#pragma unroll
        for (int i = 0; i < 6; i++) {
            int n = i * 64 + sr;
            bf8 b = *(const bf8*)(WbT + (size_t)n * F_IN + k0 + sko);
            *(bf8*)(&Bs[n * XS_STRIDE + sko]) = b;
        }
        __syncthreads();
        if (k0 + 32 < F_IN) {    // prefetch next X chunk under the MFMAs
            p0 = *(const float4*)(xrp + k0 + 32 + sko);
            p1 = *(const float4*)(xrp + k0 + 32 + sko + 4);
        }
        bf8 ar[4], br[6];
#pragma unroll
        for (int at = 0; at < 4; at++)
            ar[at] = *(const bf8*)(&Xs[(at * 16 + l15) * XS_STRIDE + quad * 8]);
#pragma unroll
        for (int nt = 0; nt < 6; nt++)
            br[nt] = *(const bf8*)(&Bs[(w * 96 + nt * 16 + l15) * XS_STRIDE + quad * 8]);
#pragma unroll
        for (int at = 0; at < 4; at++)
#pragma unroll
            for (int nt = 0; nt < 6; nt++)
                acc[at][nt] = __builtin_amdgcn_mfma_f32_16x16x32_bf16(ar[at], br[nt], acc[at][nt], 0, 0, 0);
    }

    const int splits[4] = {6, 2, 4, 0};
    int split = splits[w];
    float asv[6], adv[6];
#pragma unroll
    for (int nt = 0; nt < 6; nt++) {
        int c = w * 96 + nt * 16 + l15;
        asv[nt] = att_src[c];
        adv[nt] = att_dst[c];
    }
#pragma unroll
    for (int at = 0; at < 4; at++) {
#pragma unroll
        for (int r = 0; r < 4; r++) {
            float paS = 0.f, pbS = 0.f, paD = 0.f, pbD = 0.f;
#pragma unroll
            for (int nt = 0; nt < 6; nt++) {
                float v = acc[at][nt][r];
                if (nt < split) { paS += v * asv[nt]; paD += v * adv[nt]; }
                else            { pbS += v * asv[nt]; pbD += v * adv[nt]; }
            }
#pragma unroll
            for (int off = 1; off < 16; off <<= 1) {
                paS += __shfl_xor(paS, off); pbS += __shfl_xor(pbS, off);
                paD += __shfl_xor(paD, off); pbD += __shfl_xor(pbD, off);
            }
            if (l15 == 0) {
                int row = at * 16 + quad * 4 + r;
                lsS[row][w * 2 + 0] = paS; lsS[row][w * 2 + 1] = pbS;
                lsD[row][w * 2 + 0] = paD; lsD[row][w * 2 + 1] = pbD;
            }
        }
    }
#pragma unroll
    for (int at = 0; at < 4; at++) {
#pragma unroll
        for (int nt = 0; nt < 6; nt++) {
#pragma unroll
            for (int r = 0; r < 4; r++) {
                float v = acc[at][nt][r];
                float vp = __shfl_xor(v, 1);
                int node = rbase + at * 16 + quad * 4 + r;
                if (!(lane & 1) && node < N) {
                    unsigned pk = (unsigned)bfr(v) | ((unsigned)bfr(vp) << 16);
                    Hb[(size_t)node * 192 + w * 48 + nt * 8 + (l15 >> 1)] = pk;
                }
            }
        }
    }
    __syncthreads();
    if (t < 64) {
        int node = rbase + t;
        if (node < N) {
            aSrcO[node * 3 + 0] = lsS[t][0] + lsS[t][2];
            aSrcO[node * 3 + 1] = lsS[t][3] + lsS[t][4];
            aSrcO[node * 3 + 2] = lsS[t][5] + lsS[t][7];
            aDstO[node * 3 + 0] = lsD[t][0] + lsD[t][2];
            aDstO[node * 3 + 1] = lsD[t][3] + lsD[t][4];
            aDstO[node * 3 + 2] = lsD[t][5] + lsD[t][7];
        }
    }
}

// ---- K2: chunk scan + LAST-BLOCK scans bsums (capture-safe fusion via
//      device-scope atomic counter + threadfence; no cooperative launch) ----
__global__ __launch_bounds__(256) void scan_k(const int* __restrict__ count,
                                              int* __restrict__ offsets,
                                              int* __restrict__ bsums,
                                              int* __restrict__ scnt, int N) {
    __shared__ int tmp[256];
    __shared__ int last;
    int t = threadIdx.x;
    int i = blockIdx.x * 256 + t;
    int v = (i < N) ? count[i] : 0;
    tmp[t] = v;
    __syncthreads();
    for (int off = 1; off < 256; off <<= 1) {
        int x = (t >= off) ? tmp[t - off] : 0;
        __syncthreads();
        tmp[t] += x;
        __syncthreads();
    }
    if (i < N) offsets[i] = tmp[t] - v;
    if (t == 255) bsums[blockIdx.x] = tmp[255];
    __threadfence();
    if (t == 0) last = (atomicAdd(scnt, 1) == (int)gridDim.x - 1);
    __syncthreads();
    if (last) {
        __threadfence();
        int NB = (int)gridDim.x;
        int bv = (t < NB) ? bsums[t] : 0;
        tmp[t] = bv;
        __syncthreads();
        for (int off = 1; off < 256; off <<= 1) {
            int x = (t >= off) ? tmp[t - off] : 0;
            __syncthreads();
            tmp[t] += x;
            __syncthreads();
        }
        if (t < NB) bsums[t] = tmp[t] - bv;
    }
}

// ---- K3: scatter src into CSR — plain write via rank + bsums add ----
__global__ __launch_bounds__(256) void scatter_k(const int* __restrict__ ei,
                                                 const int* __restrict__ rank,
                                                 const int* __restrict__ offsets,
                                                 const int* __restrict__ bsums,
                                                 int* __restrict__ csr_src, int E, int N) {
    int e = blockIdx.x * 256 + threadIdx.x;
    int ET = E + N;
    if (e >= ET) return;
    int s, d;
    if (e < E) { s = ei[e]; d = ei[E + e]; } else { s = e - E; d = s; }
    csr_src[offsets[d] + bsums[d >> 8] + rank[e]] = s;
}

// ---- K4: fused softmax + aggregation, one wave per dst ----
__global__ __launch_bounds__(256) void aggregate_k(const unsigned* __restrict__ Hb,
                                                   const int* __restrict__ csr_src,
                                                   const int* __restrict__ offsets,
                                                   const int* __restrict__ bsums,
                                                   const int* __restrict__ count,
                                                   const float* __restrict__ a_src,
                                                   const float* __restrict__ a_dst,
                                                   const float* __restrict__ bias,
                                                   unsigned* __restrict__ outb, int N) {
    int wid = blockIdx.x * 4 + (threadIdx.x >> 6);
    int lane = threadIdx.x & 63;
    if (wid >= N) return;
    int start = offsets[wid] + bsums[wid >> 8];
    int n = count[wid];
    float ad0 = a_dst[wid * 3 + 0], ad1 = a_dst[wid * 3 + 1], ad2 = a_dst[wid * 3 + 2];
    float a0l = 0.f, a0h = 0.f, a1l = 0.f, a1h = 0.f, a2l = 0.f, a2h = 0.f;

    if (n <= 64) {
        int sreg = 0;
        float l0 = -INFINITY, l1 = -INFINITY, l2 = -INFINITY;
        if (lane < n) {
            sreg = csr_src[start + lane];
            l0 = lrelu(a_src[sreg * 3 + 0] + ad0);
            l1 = lrelu(a_src[sreg * 3 + 1] + ad1);
            l2 = lrelu(a_src[sreg * 3 + 2] + ad2);
        }
        float m0 = l0, m1 = l1, m2 = l2;
#pragma unroll
        for (int off = 1; off < 64; off <<= 1) {
            m0 = fmaxf(m0, __shfl_xor(m0, off));
            m1 = fmaxf(m1, __shfl_xor(m1, off));
            m2 = fmaxf(m2, __shfl_xor(m2, off));
        }
        float e0 = (lane < n) ? expf(l0 - m0) : 0.f;
        float e1 = (lane < n) ? expf(l1 - m1) : 0.f;
        float e2 = (lane < n) ? expf(l2 - m2) : 0.f;
        float s0 = e0, s1 = e1, s2 = e2;
#pragma unroll
        for (int off = 1; off < 64; off <<= 1) {
            s0 += __shfl_xor(s0, off);
            s1 += __shfl_xor(s1, off);
            s2 += __shfl_xor(s2, off);
        }
        float w0r = e0 / (s0 + 1e-16f);
        float w1r = e1 / (s1 + 1e-16f);
        float w2r = e2 / (s2 + 1e-16f);
        int j = 0;
        for (; j + 8 <= n; j += 8) {
            int idx[8];
#pragma unroll
            for (int q = 0; q < 8; q++) idx[q] = __shfl(sreg, j + q);
            unsigned u0[8], u1[8], u2[8];
#pragma unroll
            for (int q = 0; q < 8; q++) {
                const unsigned* h = Hb + (size_t)idx[q] * 192;
                u0[q] = h[lane]; u1[q] = h[lane + 64]; u2[q] = h[lane + 128];
            }
#pragma unroll
            for (int q = 0; q < 8; q++) {
                float wq0 = __shfl(w0r, j + q);
                float wq1 = __shfl(w1r, j + q);
                float wq2 = __shfl(w2r, j + q);
                a0l += wq0 * bflo(u0[q]); a0h += wq0 * bfhi(u0[q]);
                a1l += wq1 * bflo(u1[q]); a1h += wq1 * bfhi(u1[q]);
                a2l += wq2 * bflo(u2[q]); a2h += wq2 * bfhi(u2[q]);
            }
        }
        for (; j < n; j++) {
            int si = __shfl(sreg, j);
            const unsigned* h = Hb + (size_t)si * 192;
            unsigned u0 = h[lane], u1 = h[lane + 64], u2 = h[lane + 128];
            float w0 = __shfl(w0r, j), w1 = __shfl(w1r, j), w2 = __shfl(w2r, j);
            a0l += w0 * bflo(u0); a0h += w0 * bfhi(u0);
            a1l += w1 * bflo(u1); a1h += w1 * bfhi(u1);
            a2l += w2 * bflo(u2); a2h += w2 * bfhi(u2);
        }
    } else {
        float m0 = -INFINITY, m1 = -INFINITY, m2 = -INFINITY;
        for (int j = lane; j < n; j += 64) {
            int s = csr_src[start + j];
            m0 = fmaxf(m0, lrelu(a_src[s * 3 + 0] + ad0));
            m1 = fmaxf(m1, lrelu(a_src[s * 3 + 1] + ad1));
            m2 = fmaxf(m2, lrelu(a_src[s * 3 + 2] + ad2));
        }
#pragma unroll
        for (int off = 1; off < 64; off <<= 1) {
            m0 = fmaxf(m0, __shfl_xor(m0, off));
            m1 = fmaxf(m1, __shfl_xor(m1, off));
            m2 = fmaxf(m2, __shfl_xor(m2, off));
        }
        float s0 = 0.f, s1 = 0.f, s2 = 0.f;
        for (int j = lane; j < n; j += 64) {
            int s = csr_src[start + j];
            s0 += expf(lrelu(a_src[s * 3 + 0] + ad0) - m0);
            s1 += expf(lrelu(a_src[s * 3 + 1] + ad1) - m1);
            s2 += expf(lrelu(a_src[s * 3 + 2] + ad2) - m2);
        }
#pragma unroll
        for (int off = 1; off < 64; off <<= 1) {
            s0 += __shfl_xor(s0, off);
            s1 += __shfl_xor(s1, off);
            s2 += __shfl_xor(s2, off);
        }
        float i0 = 1.f / (s0 + 1e-16f), i1 = 1.f / (s1 + 1e-16f), i2 = 1.f / (s2 + 1e-16f);
        for (int j = 0; j < n; j++) {
            int s = csr_src[start + j];
            float w0 = expf(lrelu(a_src[s * 3 + 0] + ad0) - m0) * i0;
            float w1 = expf(lrelu(a_src[s * 3 + 1] + ad1) - m1) * i1;
            float w2 = expf(lrelu(a_src[s * 3 + 2] + ad2) - m2) * i2;
            const unsigned* h = Hb + (size_t)s * 192;
            unsigned u0 = h[lane], u1 = h[lane + 64], u2 = h[lane + 128];
            a0l += w0 * bflo(u0); a0h += w0 * bfhi(u0);
            a1l += w1 * bflo(u1); a1h += w1 * bfhi(u1);
            a2l += w2 * bflo(u2); a2h += w2 * bfhi(u2);
        }
    }

    unsigned* orow = outb + (size_t)wid * 192;
    int c0 = 2 * lane;
    float b0 = bias[c0], b1 = bias[c0 + 1];
    float b2 = bias[128 + c0], b3 = bias[128 + c0 + 1];
    float b4 = bias[256 + c0], b5 = bias[256 + c0 + 1];
    float v, x0, x1;
    unsigned pk;
    v = a0l + b0; x0 = (v > 0.f) ? v : 0.f;
    v = a0h + b1; x1 = (v > 0.f) ? v : 0.f;
    pk = (unsigned)bfr(x0) | ((unsigned)bfr(x1) << 16);
    orow[lane] = pk;
    v = a1l + b2; x0 = (v > 0.f) ? v : 0.f;
    v = a1h + b3; x1 = (v > 0.f) ? v : 0.f;
    pk = (unsigned)bfr(x0) | ((unsigned)bfr(x1) << 16);
    orow[64 + lane] = pk;
    v = a2l + b4; x0 = (v > 0.f) ? v : 0.f;
    v = a2h + b5; x1 = (v > 0.f) ? v : 0.f;
    pk = (unsigned)bfr(x0) | ((unsigned)bfr(x1) << 16);
    orow[128 + lane] = pk;
}

// ---- K5: segment-sum pool; LAST block also runs the FC (capture-safe) ----
__global__ __launch_bounds__(192) void pool_fc_k(const unsigned* __restrict__ outb,
                                                 const int* __restrict__ gstart,
                                                 float* __restrict__ pooled,
                                                 const float* __restrict__ fc_w,
                                                 const float* __restrict__ fc_b,
                                                 float* __restrict__ out,
                                                 int* __restrict__ pcnt) {
    __shared__ int last;
    int g = blockIdx.x;
    int chunk = blockIdx.y;
    int t = threadIdx.x;
    int lo = gstart[g], hi = gstart[g + 1];
    float al = 0.f, ah = 0.f;
    for (int r = lo + chunk; r < hi; r += 8) {
        unsigned u = outb[(size_t)r * 192 + t];
        al += bflo(u);
        ah += bfhi(u);
    }
    atomicAdd(&pooled[g * HO + 2 * t], al);
    atomicAdd(&pooled[g * HO + 2 * t + 1], ah);
    __threadfence();
    if (t == 0) last = (atomicAdd(pcnt, 1) == (int)(gridDim.x * gridDim.y) - 1);
    __syncthreads();
    if (last) {
        __threadfence();
        int wv = t >> 6, lane = t & 63;      // 3 waves round-robin over 64 graphs
        for (int gg = wv; gg < NGRAPH; gg += 3) {
            float a0 = 0.f, a1 = 0.f;
#pragma unroll
            for (int k = 0; k < 6; k++) {
                int c = lane + 64 * k;
                float pv = pooled[gg * HO + c];
                a0 += pv * fc_w[c * 2 + 0];
                a1 += pv * fc_w[c * 2 + 1];
            }
#pragma unroll
            for (int off = 32; off > 0; off >>= 1) {
                a0 += __shfl_down(a0, off);
                a1 += __shfl_down(a1, off);
            }
            if (lane == 0) {
                float cnt = fmaxf((float)(gstart[gg + 1] - gstart[gg]), 1.0f);
                out[gg * 2 + 0] = a0 / cnt + fc_b[0];
                out[gg * 2 + 1] = a1 / cnt + fc_b[1];
            }
        }
    }
}

extern "C" void kernel_launch(void* const* d_in, const int* in_sizes, int n_in,
                              void* d_out, int out_size, void* d_ws, size_t ws_size,
                              hipStream_t stream) {
    const float* x       = (const float*)d_in[0];
    const int*   ei      = (const int*)d_in[1];
    const int*   batch   = (const int*)d_in[2];
    const float* W       = (const float*)d_in[3];
    const float* att_src = (const float*)d_in[4];
    const float* att_dst = (const float*)d_in[5];
    const float* bias    = (const float*)d_in[6];
    const float* fc_w    = (const float*)d_in[7];
    const float* fc_b    = (const float*)d_in[8];
    float* out = (float*)d_out;

    const int N = in_sizes[2];
    const int E = in_sizes[1] / 2;
    const int ET = E + N;

    char* p = (char*)d_ws;
    auto alloc = [&](size_t bytes) -> char* {
        char* r = p;
        p += (bytes + 255) & ~(size_t)255;
        return r;
    };
    short*    wbt    = (short*)alloc((size_t)HO * F_IN * 2);
    unsigned* hb     = (unsigned*)alloc((size_t)N * 192 * 4);
    unsigned* outb   = (unsigned*)alloc((size_t)N * 192 * 4);
    float*    a_src  = (float*)alloc((size_t)N * 3 * 4);
    float*    a_dst  = (float*)alloc((size_t)N * 3 * 4);
    char*     zstart = p;
    int*      count  = (int*)alloc((size_t)N * 4);              // zeroed
    float*    pooled = (float*)alloc((size_t)NGRAPH * HO * 4);  // zeroed
    int*      scnt   = (int*)alloc(256);                        // zeroed
    int*      pcnt   = (int*)alloc(256);                        // zeroed
    size_t    zbytes = (size_t)(p - zstart);
    int*      offsets = (int*)alloc((size_t)N * 4);
    int*      rank    = (int*)alloc((size_t)ET * 4);
    int*      bsums   = (int*)alloc(4096);
    int*      gstart  = (int*)alloc(1024);
    int*      csr_src = (int*)alloc((size_t)ET * 4);

    hipMemsetAsync(zstart, 0, zbytes, stream);

    int NBc = (ET + 255) / 256;
    misc_k<<<NBc + 384 + 1, 256, 0, stream>>>(ei, W, batch, count, rank, wbt, gstart,
                                              NBc, E, N);
    gemm_att<<<(N + 63) / 64, 256, 0, stream>>>(x, wbt, att_src, att_dst,
                                                hb, a_src, a_dst, N);
    int NB = (N + 255) / 256;
    scan_k<<<NB, 256, 0, stream>>>(count, offsets, bsums, scnt, N);
    scatter_k<<<(ET + 255) / 256, 256, 0, stream>>>(ei, rank, offsets, bsums, csr_src, E, N);
    aggregate_k<<<(N + 3) / 4, 256, 0, stream>>>(hb, csr_src, offsets, bsums, count,
                                                 a_src, a_dst, bias, outb, N);
    dim3 pg(NGRAPH, 8);
    pool_fc_k<<<pg, 192, 0, stream>>>(outb, gstart, pooled, fc_w, fc_b, out, pcnt);

    (void)n_in; (void)out_size; (void)ws_size;
}

// Round 13
// 322.215 us; speedup vs baseline: 1.1552x; 1.1552x over previous
//
#include <hip/hip_runtime.h>
#include <hip/hip_bf16.h>
#include <math.h>

#define HEADS 3
#define HO 384
#define NGRAPH 64
#define F_IN 256
#define SLOPE 0.2f

typedef __attribute__((ext_vector_type(8))) short bf8;
typedef __attribute__((ext_vector_type(4))) float f4;

// ---- bf16 helpers ----
__device__ __forceinline__ unsigned short bfr(float f) {
    unsigned u = __float_as_uint(f);
    u += 0x7fffu + ((u >> 16) & 1u);
    return (unsigned short)(u >> 16);
}
__device__ __forceinline__ float bflo(unsigned u) { return __uint_as_float(u << 16); }
__device__ __forceinline__ float bfhi(unsigned u) { return __uint_as_float(u & 0xffff0000u); }
__device__ __forceinline__ float lrelu(float v) { return (v > 0.f) ? v : SLOPE * v; }

// ---- K0: fused misc pre-pass (block-range dispatch):
//   blocks [0, NBc)       : degree count + per-edge rank (atomic returns rank)
//   blocks [NBc, NBc+384) : W -> WbT bf16 transpose-convert
//   block  NBc+384        : per-graph start offsets (batch sorted)
__global__ __launch_bounds__(256) void misc_k(const int* __restrict__ ei,
                                              const float* __restrict__ W,
                                              const int* __restrict__ batch,
                                              int* __restrict__ count,
                                              int* __restrict__ rank,
                                              short* __restrict__ WbT,
                                              int* __restrict__ gstart,
                                              int NBc, int E, int N) {
    int b = blockIdx.x;
    if (b < NBc) {
        int e = b * 256 + threadIdx.x;
        int ET = E + N;
        if (e >= ET) return;
        int d = (e < E) ? ei[E + e] : (e - E);
        rank[e] = atomicAdd(&count[d], 1);   // unique within-dst rank
    } else if (b < NBc + 384) {
        int n = b - NBc;
        int k = threadIdx.x;
        WbT[n * 256 + k] = (short)bfr(W[(size_t)k * HO + n]);
    } else {
        int g = threadIdx.x;
        if (g > NGRAPH) return;
        int lo = 0, hi = N;
        while (lo < hi) { int mid = (lo + hi) >> 1; if (batch[mid] < g) lo = mid + 1; else hi = mid; }
        gstart[g] = lo;
    }
}

// ---- K1: LDS-staged bf16 MFMA GEMM + attention-dot epilogue (best measured:
// 256 thr, X+B staged in LDS, X register-prefetched one chunk ahead) ----
#define XS_STRIDE 40
__global__ __launch_bounds__(256, 3) void gemm_att(const float* __restrict__ X,
                                                   const short* __restrict__ WbT,
                                                   const float* __restrict__ att_src,
                                                   const float* __restrict__ att_dst,
                                                   unsigned* __restrict__ Hb,
                                                   float* __restrict__ aSrcO,
                                                   float* __restrict__ aDstO, int N) {
    __shared__ short Xs[64 * XS_STRIDE];
    __shared__ short Bs[384 * XS_STRIDE];
    __shared__ float lsS[64][8];
    __shared__ float lsD[64][8];
    int t = threadIdx.x;
    int w = t >> 6, lane = t & 63;
    int quad = lane >> 4, l15 = lane & 15;
    int rbase = blockIdx.x * 64;

    int sr = t >> 2;             // 0..63 (X row)
    int sko = (t & 3) * 8;       // 0,8,16,24
    int xrow = rbase + sr;
    xrow = (xrow < N) ? xrow : (N - 1);   // clamped rows never stored
    const float* xrp = X + (size_t)xrow * F_IN;

    f4 acc[4][6] = {};

    float4 p0 = *(const float4*)(xrp + sko);
    float4 p1 = *(const float4*)(xrp + sko + 4);

    for (int k0 = 0; k0 < F_IN; k0 += 32) {
        __syncthreads();
        {
            bf8 pk;
            pk[0] = (short)bfr(p0.x); pk[1] = (short)bfr(p0.y);
            pk[2] = (short)bfr(p0.z); pk[3] = (short)bfr(p0.w);
            pk[4] = (short)bfr(p1.x); pk[5] = (short)bfr(p1.y);
            pk[6] = (short)bfr(p1.z); pk[7] = (short)bfr(p1.w);
            *(bf8*)(&Xs[sr * XS_STRIDE + sko]) = pk;
        }
#pragma unroll
        for (int i = 0; i < 6; i++) {
            int n = i * 64 + sr;
            bf8 b = *(const bf8*)(WbT + (size_t)n * F_IN + k0 + sko);
            *(bf8*)(&Bs[n * XS_STRIDE + sko]) = b;
        }
        __syncthreads();
        if (k0 + 32 < F_IN) {    // prefetch next X chunk under the MFMAs
            p0 = *(const float4*)(xrp + k0 + 32 + sko);
            p1 = *(const float4*)(xrp + k0 + 32 + sko + 4);
        }
        bf8 ar[4], br[6];
#pragma unroll
        for (int at = 0; at < 4; at++)
            ar[at] = *(const bf8*)(&Xs[(at * 16 + l15) * XS_STRIDE + quad * 8]);
#pragma unroll
        for (int nt = 0; nt < 6; nt++)
            br[nt] = *(const bf8*)(&Bs[(w * 96 + nt * 16 + l15) * XS_STRIDE + quad * 8]);
#pragma unroll
        for (int at = 0; at < 4; at++)
#pragma unroll
            for (int nt = 0; nt < 6; nt++)
                acc[at][nt] = __builtin_amdgcn_mfma_f32_16x16x32_bf16(ar[at], br[nt], acc[at][nt], 0, 0, 0);
    }

    // ---- attention-dot epilogue ----
    // w=0: all head0 (split 6) | w=1: nt<2 head0, rest head1 (split 2)
    // w=2: nt<4 head1, rest head2 (split 4) | w=3: all head2 (split 0)
    const int splits[4] = {6, 2, 4, 0};
    int split = splits[w];
    float asv[6], adv[6];
#pragma unroll
    for (int nt = 0; nt < 6; nt++) {
        int c = w * 96 + nt * 16 + l15;
        asv[nt] = att_src[c];
        adv[nt] = att_dst[c];
    }
#pragma unroll
    for (int at = 0; at < 4; at++) {
#pragma unroll
        for (int r = 0; r < 4; r++) {
            float paS = 0.f, pbS = 0.f, paD = 0.f, pbD = 0.f;
#pragma unroll
            for (int nt = 0; nt < 6; nt++) {
                float v = acc[at][nt][r];
                if (nt < split) { paS += v * asv[nt]; paD += v * adv[nt]; }
                else            { pbS += v * asv[nt]; pbD += v * adv[nt]; }
            }
#pragma unroll
            for (int off = 1; off < 16; off <<= 1) {
                paS += __shfl_xor(paS, off); pbS += __shfl_xor(pbS, off);
                paD += __shfl_xor(paD, off); pbD += __shfl_xor(pbD, off);
            }
            if (l15 == 0) {
                int row = at * 16 + quad * 4 + r;
                lsS[row][w * 2 + 0] = paS; lsS[row][w * 2 + 1] = pbS;
                lsD[row][w * 2 + 0] = paD; lsD[row][w * 2 + 1] = pbD;
            }
        }
    }
    // ---- Hb store (C/D layout: col = lane&15, row = quad*4 + reg) ----
#pragma unroll
    for (int at = 0; at < 4; at++) {
#pragma unroll
        for (int nt = 0; nt < 6; nt++) {
#pragma unroll
            for (int r = 0; r < 4; r++) {
                float v = acc[at][nt][r];
                float vp = __shfl_xor(v, 1);
                int node = rbase + at * 16 + quad * 4 + r;
                if (!(lane & 1) && node < N) {
                    unsigned pk = (unsigned)bfr(v) | ((unsigned)bfr(vp) << 16);
                    Hb[(size_t)node * 192 + w * 48 + nt * 8 + (l15 >> 1)] = pk;
                }
            }
        }
    }
    __syncthreads();
    if (t < 64) {
        int node = rbase + t;
        if (node < N) {
            aSrcO[node * 3 + 0] = lsS[t][0] + lsS[t][2];
            aSrcO[node * 3 + 1] = lsS[t][3] + lsS[t][4];
            aSrcO[node * 3 + 2] = lsS[t][5] + lsS[t][7];
            aDstO[node * 3 + 0] = lsD[t][0] + lsD[t][2];
            aDstO[node * 3 + 1] = lsD[t][3] + lsD[t][4];
            aDstO[node * 3 + 2] = lsD[t][5] + lsD[t][7];
        }
    }
}

// ---- K2a/b/c: hierarchical exclusive scan ----
__global__ __launch_bounds__(256) void scan_a(const int* __restrict__ count,
                                              int* __restrict__ offsets,
                                              int* __restrict__ bsums, int N) {
    __shared__ int tmp[256];
    int t = threadIdx.x;
    int i = blockIdx.x * 256 + t;
    int v = (i < N) ? count[i] : 0;
    tmp[t] = v;
    __syncthreads();
    for (int off = 1; off < 256; off <<= 1) {
        int x = (t >= off) ? tmp[t - off] : 0;
        __syncthreads();
        tmp[t] += x;
        __syncthreads();
    }
    if (i < N) offsets[i] = tmp[t] - v;
    if (t == 255) bsums[blockIdx.x] = tmp[255];
}

__global__ __launch_bounds__(256) void scan_b(int* __restrict__ bsums, int NB) {
    __shared__ int tmp[256];
    int t = threadIdx.x;
    int v = (t < NB) ? bsums[t] : 0;
    tmp[t] = v;
    __syncthreads();
    for (int off = 1; off < 256; off <<= 1) {
        int x = (t >= off) ? tmp[t - off] : 0;
        __syncthreads();
        tmp[t] += x;
        __syncthreads();
    }
    if (t < NB) bsums[t] = tmp[t] - v;
}

__global__ __launch_bounds__(256) void scan_c(int* __restrict__ offsets,
                                              const int* __restrict__ bsums, int N) {
    int i = blockIdx.x * 256 + threadIdx.x;
    if (i < N) offsets[i] += bsums[blockIdx.x];
}

// ---- K3: scatter src index into CSR — plain write via precomputed rank ----
__global__ __launch_bounds__(256) void scatter_k(const int* __restrict__ ei,
                                                 const int* __restrict__ rank,
                                                 const int* __restrict__ offsets,
                                                 int* __restrict__ csr_src, int E, int N) {
    int e = blockIdx.x * 256 + threadIdx.x;
    int ET = E + N;
    if (e >= ET) return;
    int s, d;
    if (e < E) { s = ei[e]; d = ei[E + e]; } else { s = e - E; d = s; }
    csr_src[offsets[d] + rank[e]] = s;
}

// ---- K4: fused softmax + aggregation, one wave per dst, 8-edge unroll ----
__global__ __launch_bounds__(256) void aggregate_k(const unsigned* __restrict__ Hb,
                                                   const int* __restrict__ csr_src,
                                                   const int* __restrict__ offsets,
                                                   const int* __restrict__ count,
                                                   const float* __restrict__ a_src,
                                                   const float* __restrict__ a_dst,
                                                   const float* __restrict__ bias,
                                                   unsigned* __restrict__ outb, int N) {
    int wid = blockIdx.x * 4 + (threadIdx.x >> 6);
    int lane = threadIdx.x & 63;
    if (wid >= N) return;
    int start = offsets[wid], n = count[wid];
    float ad0 = a_dst[wid * 3 + 0], ad1 = a_dst[wid * 3 + 1], ad2 = a_dst[wid * 3 + 2];
    float a0l = 0.f, a0h = 0.f, a1l = 0.f, a1h = 0.f, a2l = 0.f, a2h = 0.f;

    if (n <= 64) {
        int sreg = 0;
        float l0 = -INFINITY, l1 = -INFINITY, l2 = -INFINITY;
        if (lane < n) {
            sreg = csr_src[start + lane];
            l0 = lrelu(a_src[sreg * 3 + 0] + ad0);
            l1 = lrelu(a_src[sreg * 3 + 1] + ad1);
            l2 = lrelu(a_src[sreg * 3 + 2] + ad2);
        }
        float m0 = l0, m1 = l1, m2 = l2;
#pragma unroll
        for (int off = 1; off < 64; off <<= 1) {
            m0 = fmaxf(m0, __shfl_xor(m0, off));
            m1 = fmaxf(m1, __shfl_xor(m1, off));
            m2 = fmaxf(m2, __shfl_xor(m2, off));
        }
        float e0 = (lane < n) ? expf(l0 - m0) : 0.f;
        float e1 = (lane < n) ? expf(l1 - m1) : 0.f;
        float e2 = (lane < n) ? expf(l2 - m2) : 0.f;
        float s0 = e0, s1 = e1, s2 = e2;
#pragma unroll
        for (int off = 1; off < 64; off <<= 1) {
            s0 += __shfl_xor(s0, off);
            s1 += __shfl_xor(s1, off);
            s2 += __shfl_xor(s2, off);
        }
        float w0r = e0 / (s0 + 1e-16f);
        float w1r = e1 / (s1 + 1e-16f);
        float w2r = e2 / (s2 + 1e-16f);
        int j = 0;
        for (; j + 8 <= n; j += 8) {
            int idx[8];
#pragma unroll
            for (int q = 0; q < 8; q++) idx[q] = __shfl(sreg, j + q);
            unsigned u0[8], u1[8], u2[8];
#pragma unroll
            for (int q = 0; q < 8; q++) {
                const unsigned* h = Hb + (size_t)idx[q] * 192;
                u0[q] = h[lane]; u1[q] = h[lane + 64]; u2[q] = h[lane + 128];
            }
#pragma unroll
            for (int q = 0; q < 8; q++) {
                float wq0 = __shfl(w0r, j + q);
                float wq1 = __shfl(w1r, j + q);
                float wq2 = __shfl(w2r, j + q);
                a0l += wq0 * bflo(u0[q]); a0h += wq0 * bfhi(u0[q]);
                a1l += wq1 * bflo(u1[q]); a1h += wq1 * bfhi(u1[q]);
                a2l += wq2 * bflo(u2[q]); a2h += wq2 * bfhi(u2[q]);
            }
        }
        for (; j < n; j++) {
            int si = __shfl(sreg, j);
            const unsigned* h = Hb + (size_t)si * 192;
            unsigned u0 = h[lane], u1 = h[lane + 64], u2 = h[lane + 128];
            float w0 = __shfl(w0r, j), w1 = __shfl(w1r, j), w2 = __shfl(w2r, j);
            a0l += w0 * bflo(u0); a0h += w0 * bfhi(u0);
            a1l += w1 * bflo(u1); a1h += w1 * bfhi(u1);
            a2l += w2 * bflo(u2); a2h += w2 * bfhi(u2);
        }
    } else {
        float m0 = -INFINITY, m1 = -INFINITY, m2 = -INFINITY;
        for (int j = lane; j < n; j += 64) {
            int s = csr_src[start + j];
            m0 = fmaxf(m0, lrelu(a_src[s * 3 + 0] + ad0));
            m1 = fmaxf(m1, lrelu(a_src[s * 3 + 1] + ad1));
            m2 = fmaxf(m2, lrelu(a_src[s * 3 + 2] + ad2));
        }
#pragma unroll
        for (int off = 1; off < 64; off <<= 1) {
            m0 = fmaxf(m0, __shfl_xor(m0, off));
            m1 = fmaxf(m1, __shfl_xor(m1, off));
            m2 = fmaxf(m2, __shfl_xor(m2, off));
        }
        float s0 = 0.f, s1 = 0.f, s2 = 0.f;
        for (int j = lane; j < n; j += 64) {
            int s = csr_src[start + j];
            s0 += expf(lrelu(a_src[s * 3 + 0] + ad0) - m0);
            s1 += expf(lrelu(a_src[s * 3 + 1] + ad1) - m1);
            s2 += expf(lrelu(a_src[s * 3 + 2] + ad2) - m2);
        }
#pragma unroll
        for (int off = 1; off < 64; off <<= 1) {
            s0 += __shfl_xor(s0, off);
            s1 += __shfl_xor(s1, off);
            s2 += __shfl_xor(s2, off);
        }
        float i0 = 1.f / (s0 + 1e-16f), i1 = 1.f / (s1 + 1e-16f), i2 = 1.f / (s2 + 1e-16f);
        for (int j = 0; j < n; j++) {
            int s = csr_src[start + j];
            float w0 = expf(lrelu(a_src[s * 3 + 0] + ad0) - m0) * i0;
            float w1 = expf(lrelu(a_src[s * 3 + 1] + ad1) - m1) * i1;
            float w2 = expf(lrelu(a_src[s * 3 + 2] + ad2) - m2) * i2;
            const unsigned* h = Hb + (size_t)s * 192;
            unsigned u0 = h[lane], u1 = h[lane + 64], u2 = h[lane + 128];
            a0l += w0 * bflo(u0); a0h += w0 * bfhi(u0);
            a1l += w1 * bflo(u1); a1h += w1 * bfhi(u1);
            a2l += w2 * bflo(u2); a2h += w2 * bfhi(u2);
        }
    }

    unsigned* orow = outb + (size_t)wid * 192;
    int c0 = 2 * lane;
    float b0 = bias[c0], b1 = bias[c0 + 1];
    float b2 = bias[128 + c0], b3 = bias[128 + c0 + 1];
    float b4 = bias[256 + c0], b5 = bias[256 + c0 + 1];
    float v, x0, x1;
    unsigned pk;
    v = a0l + b0; x0 = (v > 0.f) ? v : 0.f;
    v = a0h + b1; x1 = (v > 0.f) ? v : 0.f;
    pk = (unsigned)bfr(x0) | ((unsigned)bfr(x1) << 16);
    orow[lane] = pk;
    v = a1l + b2; x0 = (v > 0.f) ? v : 0.f;
    v = a1h + b3; x1 = (v > 0.f) ? v : 0.f;
    pk = (unsigned)bfr(x0) | ((unsigned)bfr(x1) << 16);
    orow[64 + lane] = pk;
    v = a2l + b4; x0 = (v > 0.f) ? v : 0.f;
    v = a2h + b5; x1 = (v > 0.f) ? v : 0.f;
    pk = (unsigned)bfr(x0) | ((unsigned)bfr(x1) << 16);
    orow[128 + lane] = pk;
}

// ---- K5: segment-sum pool over contiguous per-graph row ranges ----
__global__ __launch_bounds__(192) void pool_k(const unsigned* __restrict__ outb,
                                              const int* __restrict__ gstart,
                                              float* __restrict__ pooled) {
    int g = blockIdx.x;
    int chunk = blockIdx.y;
    int t = threadIdx.x;
    int lo = gstart[g], hi = gstart[g + 1];
    float al = 0.f, ah = 0.f;
    for (int r = lo + chunk; r < hi; r += 8) {
        unsigned u = outb[(size_t)r * 192 + t];
        al += bflo(u);
        ah += bfhi(u);
    }
    atomicAdd(&pooled[g * HO + 2 * t], al);
    atomicAdd(&pooled[g * HO + 2 * t + 1], ah);
}

// ---- K6: FC over pooled means ----
__global__ __launch_bounds__(64) void fc_k(const float* __restrict__ pooled,
                                           const int* __restrict__ gstart,
                                           const float* __restrict__ fc_w,
                                           const float* __restrict__ fc_b,
                                           float* __restrict__ out) {
    int g = blockIdx.x;
    int lane = threadIdx.x;
    float a0 = 0.f, a1 = 0.f;
#pragma unroll
    for (int k = 0; k < 6; k++) {
        int c = lane + 64 * k;
        float pv = pooled[g * HO + c];
        a0 += pv * fc_w[c * 2 + 0];
        a1 += pv * fc_w[c * 2 + 1];
    }
#pragma unroll
    for (int off = 32; off > 0; off >>= 1) {
        a0 += __shfl_down(a0, off);
        a1 += __shfl_down(a1, off);
    }
    if (lane == 0) {
        float cnt = fmaxf((float)(gstart[g + 1] - gstart[g]), 1.0f);
        out[g * 2 + 0] = a0 / cnt + fc_b[0];
        out[g * 2 + 1] = a1 / cnt + fc_b[1];
    }
}

extern "C" void kernel_launch(void* const* d_in, const int* in_sizes, int n_in,
                              void* d_out, int out_size, void* d_ws, size_t ws_size,
                              hipStream_t stream) {
    const float* x       = (const float*)d_in[0];
    const int*   ei      = (const int*)d_in[1];
    const int*   batch   = (const int*)d_in[2];
    const float* W       = (const float*)d_in[3];
    const float* att_src = (const float*)d_in[4];
    const float* att_dst = (const float*)d_in[5];
    const float* bias    = (const float*)d_in[6];
    const float* fc_w    = (const float*)d_in[7];
    const float* fc_b    = (const float*)d_in[8];
    float* out = (float*)d_out;

    const int N = in_sizes[2];
    const int E = in_sizes[1] / 2;
    const int ET = E + N;

    char* p = (char*)d_ws;
    auto alloc = [&](size_t bytes) -> char* {
        char* r = p;
        p += (bytes + 255) & ~(size_t)255;
        return r;
    };
    short*    wbt    = (short*)alloc((size_t)HO * F_IN * 2);
    unsigned* hb     = (unsigned*)alloc((size_t)N * 192 * 4);
    unsigned* outb   = (unsigned*)alloc((size_t)N * 192 * 4);
    float*    a_src  = (float*)alloc((size_t)N * 3 * 4);
    float*    a_dst  = (float*)alloc((size_t)N * 3 * 4);
    char*     zstart = p;
    int*      count  = (int*)alloc((size_t)N * 4);              // zeroed
    float*    pooled = (float*)alloc((size_t)NGRAPH * HO * 4);  // zeroed
    size_t    zbytes = (size_t)(p - zstart);
    int*      offsets = (int*)alloc((size_t)N * 4);
    int*      rank    = (int*)alloc((size_t)ET * 4);
    int*      bsums   = (int*)alloc(4096);
    int*      gstart  = (int*)alloc(1024);
    int*      csr_src = (int*)alloc((size_t)ET * 4);

    hipMemsetAsync(zstart, 0, zbytes, stream);

    int NBc = (ET + 255) / 256;
    misc_k<<<NBc + 384 + 1, 256, 0, stream>>>(ei, W, batch, count, rank, wbt, gstart,
                                              NBc, E, N);
    gemm_att<<<(N + 63) / 64, 256, 0, stream>>>(x, wbt, att_src, att_dst,
                                                hb, a_src, a_dst, N);
    int NB = (N + 255) / 256;
    scan_a<<<NB, 256, 0, stream>>>(count, offsets, bsums, N);
    scan_b<<<1, 256, 0, stream>>>(bsums, NB);
    scan_c<<<NB, 256, 0, stream>>>(offsets, bsums, N);
    scatter_k<<<(ET + 255) / 256, 256, 0, stream>>>(ei, rank, offsets, csr_src, E, N);
    aggregate_k<<<(N + 3) / 4, 256, 0, stream>>>(hb, csr_src, offsets, count,
                                                 a_src, a_dst, bias, outb, N);
    dim3 pg(NGRAPH, 8);
    pool_k<<<pg, 192, 0, stream>>>(outb, gstart, pooled);
    fc_k<<<NGRAPH, 64, 0, stream>>>(pooled, gstart, fc_w, fc_b, out);

    (void)n_in; (void)out_size; (void)ws_size;
}